// Round 8
// baseline (894.834 us; speedup 1.0000x reference)
//
#include <hip/hip_runtime.h>
#include <hip/hip_bf16.h>

#define NB 8
#define CIN 3
#define HH 224
#define WW 224
#define OC 32
#define NH 8
#define HD 4
#define NHD 32   // NH*HD
#define C96 96
#define HWSZ (HH*WW)

// padded x1 layout: per channel [PH=226 rows][PW=228 cols], image (h,w) at [h+1][w+1],
// borders zero (one memset). Row stride 228 floats = 912 B (16B-divisible) so any
// 6-row tile is one contiguous 16B-aligned block -> guard-free direct-to-LDS staging.
#define PH 226
#define PW 228
#define CHS (PH*PW)      // 51528 floats per channel image

#define HT 4     // h rows per block (conv_qkv tile)
#define OCT 8    // output channels per block (proven codegen shape; 12 reg-cliffed)
#define NGB 4    // batches per qkv group dispatch

// k stored in BLOCKED-transposed layout kT[w>>2][j][w&3] (float index
// (w>>2)*896 + j*4 + (w&3), same HWSZ bytes). Conv block (4h x 224w) owns 56
// full 64B chunks -> fully dense HBM writes; attn reads float4 per 4-w step.

// direct global->LDS 16B per lane: lds dest is wave-uniform base + lane*16 (HW rule)
__device__ __forceinline__ void gld_lds16(const float* gsrc, float* ldst) {
    __builtin_amdgcn_global_load_lds(
        (const __attribute__((address_space(1))) uint32_t*)gsrc,
        (__attribute__((address_space(3))) uint32_t*)ldst,
        16, 0, 0);
}

// W2 = upd_w @ proj_w ; b2 = upd_w @ proj_b + upd_b   (1x1 conv composition)
__global__ void k_w2(const float* __restrict__ pw, const float* __restrict__ pb,
                     const float* __restrict__ uw, const float* __restrict__ ub,
                     float* __restrict__ W2, float* __restrict__ b2) {
    int c = threadIdx.x, o = threadIdx.y;  // 32x32
    float acc = 0.f;
    for (int m = 0; m < OC; ++m) acc = fmaf(uw[o*OC + m], pw[m*OC + c], acc);
    W2[o*OC + c] = acc;
    if (c == 0) {
        float bb = ub[o];
        for (int m = 0; m < OC; ++m) bb = fmaf(uw[o*OC + m], pb[m], bb);
        b2[o] = bb;
    }
}

// Tiled input conv: block = 2 h-rows x all 32 oc. Stage 3ch x 4 rows in LDS once.
// Per-output order frozen: c asc -> kh -> kw single fmaf chain, bias added after.
// Output written into the PADDED x1 layout (interior only; borders pre-zeroed).
__global__ __launch_bounds__(256) void k_conv_in_tile(const float* __restrict__ x,
                                                      const float* __restrict__ w,
                                                      const float* __restrict__ bias,
                                                      float* __restrict__ x1) {
    int h0 = blockIdx.x * 2;
    int b  = blockIdx.y;
    __shared__ float xs[CIN][4][226];
    int t = threadIdx.x;
    for (int ch = 0; ch < CIN; ++ch)
        for (int r = 0; r < 4; ++r) {
            int gh = h0 - 1 + r;
            for (int col = t; col < 226; col += 256) {
                float v = 0.f;
                if (gh >= 0 && gh < HH && col > 0 && col < 225)
                    v = x[((size_t)(b*CIN + ch)*HH + gh)*WW + (col-1)];
                xs[ch][r][col] = v;
            }
        }
    __syncthreads();
    int wv = t;
    if (wv >= WW) return;
    float xv[CIN][4][3];
    #pragma unroll
    for (int c = 0; c < CIN; ++c)
        #pragma unroll
        for (int r = 0; r < 4; ++r)
            #pragma unroll
            for (int j = 0; j < 3; ++j)
                xv[c][r][j] = xs[c][r][wv + j];
    float acc[2][OC];
    #pragma unroll
    for (int hy = 0; hy < 2; ++hy)
        for (int oc = 0; oc < OC; ++oc) acc[hy][oc] = 0.f;
    #pragma unroll
    for (int c = 0; c < CIN; ++c)
        #pragma unroll
        for (int kh = 0; kh < 3; ++kh)
            #pragma unroll
            for (int kw = 0; kw < 3; ++kw)
                for (int oc = 0; oc < OC; ++oc) {
                    float wgt = w[oc*CIN*9 + c*9 + kh*3 + kw];  // uniform -> s_load
                    #pragma unroll
                    for (int hy = 0; hy < 2; ++hy)
                        acc[hy][oc] = fmaf(xv[c][hy+kh][kw], wgt, acc[hy][oc]);
                }
    for (int oc = 0; oc < OC; ++oc) {
        float bs = bias[oc];
        #pragma unroll
        for (int hy = 0; hy < 2; ++hy)
            x1[((size_t)(b*OC + oc)*PH + (h0+hy+1))*PW + (wv+1)] = __fadd_rn(acc[hy][oc], bs);
    }
}

// Tiled qkv conv, double-buffered direct-to-LDS staging from padded x1 (r4-proven).
// Per-output accumulation order frozen: c asc -> kh -> kw, single fmaf chain.
// k-channels: LDS-assembled blocked-transposed store (full 64B chunks).
__global__ __launch_bounds__(256) void k_conv_qkv_tile(const float* __restrict__ x1g,
                                                       const float* __restrict__ w,
                                                       float* __restrict__ qk4,
                                                       float* __restrict__ vbg) {
    int h0 = blockIdx.x * HT;          // 56 tiles
    int og = blockIdx.y * OCT;         // 12 groups
    int z  = blockIdx.z;               // local batch
    const float* x1b = x1g + (size_t)z*OC*CHS;
    float* qk = qk4 + (size_t)z*64*HWSZ;
    float* vb = vbg + (size_t)z*OC*HWSZ;
    // main loop uses [2][1536]; k-store phase reuses flat 4480 floats (4ch x 56wb x 20)
    __shared__ float xs[2][2240];
    int t = threadIdx.x;
    int lane = t & 63, wid = t >> 6;
    int wv = t;
    float acc[HT][OCT];
    #pragma unroll
    for (int a = 0; a < HT; ++a)
        #pragma unroll
        for (int o = 0; o < OCT; ++o) acc[a][o] = 0.f;

    // stage c=0 into buf 0
    {
        const float* src = x1b + (size_t)h0*PW;
        for (int k = wid; k < 6; k += 4)
            gld_lds16(src + k*256 + lane*4, &xs[0][k*256]);
    }
    __syncthreads();

    for (int c = 0; c < OC; ++c) {
        int cur = c & 1;
        if (c + 1 < OC) {                       // prefetch next channel into other buf
            const float* src = x1b + (size_t)(c+1)*CHS + (size_t)h0*PW;
            float* dst = xs[cur ^ 1];
            for (int k = wid; k < 6; k += 4)
                gld_lds16(src + k*256 + lane*4, dst + k*256);
        }
        if (wv < WW) {
            float xv[HT+2][3];
            #pragma unroll
            for (int r = 0; r < HT+2; ++r)
                #pragma unroll
                for (int j = 0; j < 3; ++j)
                    xv[r][j] = xs[cur][r*PW + wv + j];
            #pragma unroll
            for (int o = 0; o < OCT; ++o) {
                const float* wr = w + ((size_t)(og + o)*OC + c)*9;
                #pragma unroll
                for (int kh = 0; kh < 3; ++kh)
                    #pragma unroll
                    for (int kw = 0; kw < 3; ++kw) {
                        float wgt = wr[kh*3 + kw];
                        #pragma unroll
                        for (int hy = 0; hy < HT; ++hy)
                            acc[hy][o] = fmaf(xv[hy+kh][kw], wgt, acc[hy][o]);
                    }
            }
        }
        __syncthreads();
    }
    // q and v: coalesced row stores
    if (wv < WW) {
        #pragma unroll
        for (int o = 0; o < OCT; ++o) {
            int oc = og + o;
            int rem = oc % 12;
            int r = rem >> 2, d = rem & 3;
            int n = oc / 12;
            if (r == 0) {
                #pragma unroll
                for (int hy = 0; hy < HT; ++hy)
                    qk[((size_t)(n*8 + d)*HH + (h0+hy))*WW + wv] = acc[hy][o];
            } else if (r == 2) {
                #pragma unroll
                for (int hy = 0; hy < HT; ++hy)
                    vb[((size_t)(n*4 + d)*HH + (h0+hy))*WW + wv] = acc[hy][o];
            }
        }
    }
    // k-channels (blocks have 0 or 4): assemble in LDS, store 64B-dense chunks.
    int ogm = og % 12;
    if (ogm != 8) {
        int ko = (ogm == 0) ? 4 : 0;            // o-offset of the 4 k-channels
        int n  = og / 12;
        float* kt = &xs[0][0];                  // 4480 floats, main-loop xs is dead
        if (wv < WW) {
            int wb = wv >> 2, wl = wv & 3;
            #pragma unroll
            for (int kk = 0; kk < 4; ++kk)
                #pragma unroll
                for (int hy = 0; hy < HT; ++hy)
                    kt[(kk*56 + wb)*20 + hy*4 + wl] = acc[hy][ko + kk];
        }
        __syncthreads();
        if (wv < WW) {
            int wb = wv >> 2, s = wv & 3;
            #pragma unroll
            for (int kk = 0; kk < 4; ++kk) {    // d = kk for these channels
                float4 kvv = *(const float4*)(&kt[(kk*56 + wb)*20 + s*4]);
                *(float4*)(qk + (size_t)(n*8 + 4 + kk)*HWSZ
                               + (size_t)wb*(HH*4) + (size_t)(h0 + s)*4) = kvv;
            }
        }
    }
}

// attention v8: block = 1 wave (64 threads), 8 i-rows, 4 j-columns per thread.
// Per 4-w chunk per wave: 8 uniform q LDS reads (96 cy, x4 SIMD = 384) vs
// 8ii*4jj*8 = 256 VALU ops (512 cy) -> VALU-bound; k-plane re-read amortized
// over 8 rows (28 waves/plane ~ 6.3 MB L2 traffic ~ 23 us < 37 us VALU floor).
// k: adjacent float4s in blocked kT, coalesced. Dot semantics frozen: np.einsum
// SSE1 — 4 separate no-fma comp lanes over ascending w, reduce (s0+s1)+(s2+s3);
// 0.5f* exact; gumbel added last. Argmax: strict >, first j (ascending in-lane
// then smaller-j tie-break in shfl reduce). att pre-zeroed; winner-only stores.
__global__ __launch_bounds__(64) void k_attn_ri(const float* __restrict__ qk4,
                                                const float* __restrict__ gum,
                                                float* __restrict__ att,
                                                int* __restrict__ idxout,
                                                int b0) {
    int i0 = blockIdx.x * 8;
    int nd = blockIdx.y;
    int z  = blockIdx.z;
    int b  = b0 + z;
    const float* qkz = qk4 + (size_t)z*64*HWSZ;
    const float* gumb = gum + (size_t)b*NHD*HH*HH;
    float* attb = att + (size_t)b*NHD*HH*HH;
    int* idxb = idxout + (size_t)b*NHD*HH;
    int n = nd >> 2, d = nd & 3;
    const float* qb = qkz + ((size_t)(n*8 + d)*HH + i0)*WW;   // 8 rows, contiguous
    const float4* kT4 = (const float4*)(qkz + (size_t)(n*8 + 4 + d)*HWSZ);
    __shared__ __align__(16) float qs[8*WW];
    int t = threadIdx.x;
    for (int f = t; f < 8*(WW/4); f += 64)            // 448 float4, flat copy
        *(float4*)(&qs[f*4]) = *(const float4*)(qb + (size_t)f*4);
    __syncthreads();

    // accumulators [ii][jj] x 4 comps = 128 VGPR, all statically indexed.
    float s0[8][4], s1[8][4], s2[8][4], s3[8][4];
    #pragma unroll
    for (int ii = 0; ii < 8; ++ii)
        #pragma unroll
        for (int jj = 0; jj < 4; ++jj)
            { s0[ii][jj]=0.f; s1[ii][jj]=0.f; s2[ii][jj]=0.f; s3[ii][jj]=0.f; }

    for (int wb = 0; wb < 56; ++wb) {
        float4 kc[4];
        #pragma unroll
        for (int jj = 0; jj < 4; ++jj)                 // coalesced: lanes adjacent
            kc[jj] = kT4[(size_t)wb*224 + 4*t + jj];   // t>=56: in-ws garbage
        #pragma unroll
        for (int ii = 0; ii < 8; ++ii) {
            float4 qc = *(const float4*)(&qs[ii*WW + wb*4]);  // uniform -> broadcast
            #pragma unroll
            for (int jj = 0; jj < 4; ++jj) {
                s0[ii][jj] = __fadd_rn(s0[ii][jj], __fmul_rn(qc.x, kc[jj].x));
                s1[ii][jj] = __fadd_rn(s1[ii][jj], __fmul_rn(qc.y, kc[jj].y));
                s2[ii][jj] = __fadd_rn(s2[ii][jj], __fmul_rn(qc.z, kc[jj].z));
                s3[ii][jj] = __fadd_rn(s3[ii][jj], __fmul_rn(qc.w, kc[jj].w));
            }
        }
    }

    #pragma unroll
    for (int ii = 0; ii < 8; ++ii) {
        float v[4];
        if (t < 56) {
            float4 gc = *(const float4*)(gumb + ((size_t)nd*HH + (i0+ii))*HH + 4*t);
            #pragma unroll
            for (int jj = 0; jj < 4; ++jj) {
                float dot = __fadd_rn(__fadd_rn(s0[ii][jj], s1[ii][jj]),
                                      __fadd_rn(s2[ii][jj], s3[ii][jj]));
                float g = (jj==0)?gc.x:(jj==1)?gc.y:(jj==2)?gc.z:gc.w;
                v[jj] = __fadd_rn(__fmul_rn(0.5f, dot), g);
            }
        } else {
            #pragma unroll
            for (int jj = 0; jj < 4; ++jj) v[jj] = -INFINITY;
        }
        float best = v[0]; int bj = (t < 56) ? 4*t : 0x7fffffff;
        #pragma unroll
        for (int jj = 1; jj < 4; ++jj)                 // ascending j, strict >
            if (v[jj] > best) { best = v[jj]; bj = 4*t + jj; }
        for (int off = 32; off > 0; off >>= 1) {       // 64-lane reduce
            float v2 = __shfl_down(best, off, 64);
            int   j2 = __shfl_down(bj,   off, 64);
            if (v2 > best || (v2 == best && j2 < bj)) { best = v2; bj = j2; }
        }
        if (t == 0) {
            idxb[nd*HH + i0 + ii] = bj;
            attb[((size_t)nd*HH + (i0 + ii))*HH + bj] = 1.f;  // rest memset 0
        }
    }
}

// A2 = W2*gather(v) + b2 per pixel — gather + 32x32 mm done ONCE, A2 written out.
__global__ __launch_bounds__(256) void k_gather_mm(const float* __restrict__ vbuf,
                                                   const int* __restrict__ idx,
                                                   const float* __restrict__ W2g,
                                                   const float* __restrict__ b2g,
                                                   float* __restrict__ A2) {
    int i = blockIdx.x, b = blockIdx.y;
    __shared__ float w2s[OC*OC];
    __shared__ float b2s[OC];
    __shared__ int   id[OC];
    for (int t = threadIdx.x; t < OC*OC; t += blockDim.x) w2s[t] = W2g[t];
    if (threadIdx.x < OC) {
        b2s[threadIdx.x] = b2g[threadIdx.x];
        id[threadIdx.x]  = idx[(b*NHD + threadIdx.x)*HH + i];
    }
    __syncthreads();
    int wv = threadIdx.x;
    if (wv >= WW) return;
    float vals[OC];
    for (int c = 0; c < OC; ++c)
        vals[c] = vbuf[((size_t)(b*OC + c)*HH + id[c])*WW + wv];
    for (int oc = 0; oc < OC; ++oc) {
        float a = b2s[oc];
        for (int c = 0; c < OC; ++c) a = fmaf(w2s[oc*OC + c], vals[c], a);
        A2[((size_t)(b*OC + oc)*HH + i)*WW + wv] = a;
    }
}

// linear float4 reduction over A2 for per-channel sum/sumsq
__global__ __launch_bounds__(256) void k_stats(const float* __restrict__ A2,
                                               float* __restrict__ sums,
                                               float* __restrict__ sumsq) {
    int oc = blockIdx.x, s = blockIdx.y;    // 16 slabs
    int t = threadIdx.x;
    float a = 0.f, a2 = 0.f;
    const int SL = HWSZ/16;                 // 3136
    for (int b = 0; b < NB; ++b) {
        const float* base = A2 + (size_t)(b*OC + oc)*HWSZ + s*SL;
        for (int e = t*4; e < SL; e += 256*4) {
            float4 v = *(const float4*)(base + e);
            a  += v.x + v.y + v.z + v.w;
            a2 += v.x*v.x + v.y*v.y + v.z*v.z + v.w*v.w;
        }
    }
    __shared__ float r1[256], r2[256];
    r1[t] = a; r2[t] = a2;
    __syncthreads();
    for (int st = 128; st > 0; st >>= 1) {
        if (t < st) { r1[t] += r1[t+st]; r2[t] += r2[t+st]; }
        __syncthreads();
    }
    if (t == 0) { atomicAdd(&sums[oc], r1[0]); atomicAdd(&sumsq[oc], r2[0]); }
}

// streaming BN + SiLU + residual from A2 (x1 read from padded layout), write fp32 out
__global__ __launch_bounds__(256) void k_final(const float* __restrict__ A2,
                                               const float* __restrict__ x1,
                                               const float* __restrict__ sums,
                                               const float* __restrict__ sumsq,
                                               const float* __restrict__ gamma,
                                               const float* __restrict__ beta,
                                               float* __restrict__ out) {
    int i = blockIdx.x, b = blockIdx.y;
    __shared__ float mean_s[OC], inv_s[OC], g_s[OC], be_s[OC];
    if (threadIdx.x < OC) {
        int oc = threadIdx.x;
        const float N = (float)(NB*HH*WW);
        float mean = sums[oc]/N;
        float var  = sumsq[oc]/N - mean*mean;
        mean_s[oc] = mean;
        inv_s[oc]  = rsqrtf(var + 1e-5f);
        g_s[oc]    = gamma[oc];
        be_s[oc]   = beta[oc];
    }
    __syncthreads();
    int wv = threadIdx.x;
    if (wv >= WW) return;
    for (int oc = 0; oc < OC; ++oc) {
        size_t o = ((size_t)(b*OC + oc)*HH + i)*WW + wv;
        float a = A2[o];
        float an = (a - mean_s[oc])*inv_s[oc]*g_s[oc] + be_s[oc];
        float sw = an / (1.f + __expf(-an));
        out[o] = sw + x1[((size_t)(b*OC + oc)*PH + (i+1))*PW + (wv+1)];
    }
}

extern "C" void kernel_launch(void* const* d_in, const int* in_sizes, int n_in,
                              void* d_out, int out_size, void* d_ws, size_t ws_size,
                              hipStream_t stream) {
    const float* x      = (const float*)d_in[0];
    const float* gumbel = (const float*)d_in[1];
    const float* in_w   = (const float*)d_in[2];
    const float* in_b   = (const float*)d_in[3];
    const float* qkv_w  = (const float*)d_in[4];
    const float* proj_w = (const float*)d_in[5];
    const float* proj_b = (const float*)d_in[6];
    const float* upd_w  = (const float*)d_in[7];
    const float* upd_b  = (const float*)d_in[8];
    const float* bng    = (const float*)d_in[9];
    const float* bnb    = (const float*)d_in[10];

    float* out = (float*)d_out;
    float* att = out + (size_t)NB*OC*HWSZ;

    // ws layout, total ~155.8 MB. A2 aliases qk4 (both 12,845,056 f) — qk dead after attn.
    float* x1   = (float*)d_ws;                      // 13,191,168 f (52.8 MB, padded)
    float* qk4  = x1 + (size_t)NB*OC*CHS;            // 12,845,056 f (51.4 MB, 4 batches)
    float* A2   = qk4;                               // alias
    float* vbuf = qk4 + (size_t)NGB*64*HWSZ;         // 12,845,056 f (51.4 MB)
    float* W2   = vbuf + (size_t)NB*OC*HWSZ;         // 1024
    float* b2   = W2 + OC*OC;                        // 32
    float* sums = b2 + OC;                           // 32
    float* sumsq= sums + OC;                         // 32
    int*   idx  = (int*)(sumsq + OC);                // 57,344 ints

    hipMemsetAsync(x1, 0, (size_t)NB*OC*CHS*sizeof(float), stream);  // zero pad borders
    hipMemsetAsync(att, 0, (size_t)NB*NHD*HH*HH*sizeof(float), stream); // one-hot base
    hipMemsetAsync(sums, 0, 2*OC*sizeof(float), stream);

    k_w2          <<<1, dim3(OC, OC), 0, stream>>>(proj_w, proj_b, upd_w, upd_b, W2, b2);
    k_conv_in_tile<<<dim3(HH/2, NB), 256, 0, stream>>>(x, in_w, in_b, x1);

    for (int g = 0; g < NB/NGB; ++g) {
        k_conv_qkv_tile<<<dim3(HH/HT, C96/OCT, NGB), 256, 0, stream>>>(
            x1 + (size_t)g*NGB*OC*CHS, qkv_w, qk4, vbuf + (size_t)g*NGB*OC*HWSZ);
        k_attn_ri<<<dim3(HH/8, NHD, NGB), 64, 0, stream>>>(
            qk4, gumbel, att, idx, g*NGB);
    }

    k_gather_mm<<<dim3(HH, NB), 256, 0, stream>>>(vbuf, idx, W2, b2, A2);
    k_stats    <<<dim3(OC, 16), 256, 0, stream>>>(A2, sums, sumsq);
    k_final    <<<dim3(HH, NB), 256, 0, stream>>>(A2, x1, sums, sumsq, bng, bnb, out);
}

// Round 9
// 750.742 us; speedup vs baseline: 1.1919x; 1.1919x over previous
//
#include <hip/hip_runtime.h>
#include <hip/hip_bf16.h>

#define NB 8
#define CIN 3
#define HH 224
#define WW 224
#define OC 32
#define NH 8
#define HD 4
#define NHD 32   // NH*HD
#define C96 96
#define HWSZ (HH*WW)

// padded x1 layout: per channel [PH=226 rows][PW=228 cols], image (h,w) at [h+1][w+1],
// borders zero (one memset). Row stride 228 floats = 912 B (16B-divisible) so any
// 6-row tile is one contiguous 16B-aligned block -> guard-free direct-to-LDS staging.
#define PH 226
#define PW 228
#define CHS (PH*PW)      // 51528 floats per channel image

#define HT 4     // h rows per block (conv_qkv tile)
#define OCT 8    // output channels per block (proven codegen shape; 12 reg-cliffed)
#define NGB 4    // batches per qkv group dispatch

// k stored in BLOCKED-transposed layout kT[w>>2][j][w&3] (float index
// (w>>2)*896 + j*4 + (w&3), same HWSZ bytes). Conv block (4h x 224w) owns 56
// full 64B chunks -> fully dense HBM writes; attn reads float4 per 4-w step.

// direct global->LDS 16B per lane: lds dest is wave-uniform base + lane*16 (HW rule)
__device__ __forceinline__ void gld_lds16(const float* gsrc, float* ldst) {
    __builtin_amdgcn_global_load_lds(
        (const __attribute__((address_space(1))) uint32_t*)gsrc,
        (__attribute__((address_space(3))) uint32_t*)ldst,
        16, 0, 0);
}

// W2 = upd_w @ proj_w ; b2 = upd_w @ proj_b + upd_b   (1x1 conv composition)
__global__ void k_w2(const float* __restrict__ pw, const float* __restrict__ pb,
                     const float* __restrict__ uw, const float* __restrict__ ub,
                     float* __restrict__ W2, float* __restrict__ b2) {
    int c = threadIdx.x, o = threadIdx.y;  // 32x32
    float acc = 0.f;
    for (int m = 0; m < OC; ++m) acc = fmaf(uw[o*OC + m], pw[m*OC + c], acc);
    W2[o*OC + c] = acc;
    if (c == 0) {
        float bb = ub[o];
        for (int m = 0; m < OC; ++m) bb = fmaf(uw[o*OC + m], pb[m], bb);
        b2[o] = bb;
    }
}

// Tiled input conv: block = 2 h-rows x all 32 oc. Stage 3ch x 4 rows in LDS once.
// Per-output order frozen: c asc -> kh -> kw single fmaf chain, bias added after.
// Output written into the PADDED x1 layout (interior only; borders pre-zeroed).
__global__ __launch_bounds__(256) void k_conv_in_tile(const float* __restrict__ x,
                                                      const float* __restrict__ w,
                                                      const float* __restrict__ bias,
                                                      float* __restrict__ x1) {
    int h0 = blockIdx.x * 2;
    int b  = blockIdx.y;
    __shared__ float xs[CIN][4][226];
    int t = threadIdx.x;
    for (int ch = 0; ch < CIN; ++ch)
        for (int r = 0; r < 4; ++r) {
            int gh = h0 - 1 + r;
            for (int col = t; col < 226; col += 256) {
                float v = 0.f;
                if (gh >= 0 && gh < HH && col > 0 && col < 225)
                    v = x[((size_t)(b*CIN + ch)*HH + gh)*WW + (col-1)];
                xs[ch][r][col] = v;
            }
        }
    __syncthreads();
    int wv = t;
    if (wv >= WW) return;
    float xv[CIN][4][3];
    #pragma unroll
    for (int c = 0; c < CIN; ++c)
        #pragma unroll
        for (int r = 0; r < 4; ++r)
            #pragma unroll
            for (int j = 0; j < 3; ++j)
                xv[c][r][j] = xs[c][r][wv + j];
    float acc[2][OC];
    #pragma unroll
    for (int hy = 0; hy < 2; ++hy)
        for (int oc = 0; oc < OC; ++oc) acc[hy][oc] = 0.f;
    #pragma unroll
    for (int c = 0; c < CIN; ++c)
        #pragma unroll
        for (int kh = 0; kh < 3; ++kh)
            #pragma unroll
            for (int kw = 0; kw < 3; ++kw)
                for (int oc = 0; oc < OC; ++oc) {
                    float wgt = w[oc*CIN*9 + c*9 + kh*3 + kw];  // uniform -> s_load
                    #pragma unroll
                    for (int hy = 0; hy < 2; ++hy)
                        acc[hy][oc] = fmaf(xv[c][hy+kh][kw], wgt, acc[hy][oc]);
                }
    for (int oc = 0; oc < OC; ++oc) {
        float bs = bias[oc];
        #pragma unroll
        for (int hy = 0; hy < 2; ++hy)
            x1[((size_t)(b*OC + oc)*PH + (h0+hy+1))*PW + (wv+1)] = __fadd_rn(acc[hy][oc], bs);
    }
}

// Tiled qkv conv, double-buffered direct-to-LDS staging from padded x1 (r4-proven).
// Per-output accumulation order frozen: c asc -> kh -> kw, single fmaf chain.
// k-channels: LDS-assembled blocked-transposed store (full 64B chunks).
__global__ __launch_bounds__(256) void k_conv_qkv_tile(const float* __restrict__ x1g,
                                                       const float* __restrict__ w,
                                                       float* __restrict__ qk4,
                                                       float* __restrict__ vbg) {
    int h0 = blockIdx.x * HT;          // 56 tiles
    int og = blockIdx.y * OCT;         // 12 groups
    int z  = blockIdx.z;               // local batch
    const float* x1b = x1g + (size_t)z*OC*CHS;
    float* qk = qk4 + (size_t)z*64*HWSZ;
    float* vb = vbg + (size_t)z*OC*HWSZ;
    // main loop uses [2][1536]; k-store phase reuses flat 4480 floats (4ch x 56wb x 20)
    __shared__ float xs[2][2240];
    int t = threadIdx.x;
    int lane = t & 63, wid = t >> 6;
    int wv = t;
    float acc[HT][OCT];
    #pragma unroll
    for (int a = 0; a < HT; ++a)
        #pragma unroll
        for (int o = 0; o < OCT; ++o) acc[a][o] = 0.f;

    // stage c=0 into buf 0
    {
        const float* src = x1b + (size_t)h0*PW;
        for (int k = wid; k < 6; k += 4)
            gld_lds16(src + k*256 + lane*4, &xs[0][k*256]);
    }
    __syncthreads();

    for (int c = 0; c < OC; ++c) {
        int cur = c & 1;
        if (c + 1 < OC) {                       // prefetch next channel into other buf
            const float* src = x1b + (size_t)(c+1)*CHS + (size_t)h0*PW;
            float* dst = xs[cur ^ 1];
            for (int k = wid; k < 6; k += 4)
                gld_lds16(src + k*256 + lane*4, dst + k*256);
        }
        if (wv < WW) {
            float xv[HT+2][3];
            #pragma unroll
            for (int r = 0; r < HT+2; ++r)
                #pragma unroll
                for (int j = 0; j < 3; ++j)
                    xv[r][j] = xs[cur][r*PW + wv + j];
            #pragma unroll
            for (int o = 0; o < OCT; ++o) {
                const float* wr = w + ((size_t)(og + o)*OC + c)*9;
                #pragma unroll
                for (int kh = 0; kh < 3; ++kh)
                    #pragma unroll
                    for (int kw = 0; kw < 3; ++kw) {
                        float wgt = wr[kh*3 + kw];
                        #pragma unroll
                        for (int hy = 0; hy < HT; ++hy)
                            acc[hy][o] = fmaf(xv[hy+kh][kw], wgt, acc[hy][o]);
                    }
            }
        }
        __syncthreads();
    }
    // q and v: coalesced row stores
    if (wv < WW) {
        #pragma unroll
        for (int o = 0; o < OCT; ++o) {
            int oc = og + o;
            int rem = oc % 12;
            int r = rem >> 2, d = rem & 3;
            int n = oc / 12;
            if (r == 0) {
                #pragma unroll
                for (int hy = 0; hy < HT; ++hy)
                    qk[((size_t)(n*8 + d)*HH + (h0+hy))*WW + wv] = acc[hy][o];
            } else if (r == 2) {
                #pragma unroll
                for (int hy = 0; hy < HT; ++hy)
                    vb[((size_t)(n*4 + d)*HH + (h0+hy))*WW + wv] = acc[hy][o];
            }
        }
    }
    // k-channels (blocks have 0 or 4): assemble in LDS, store 64B-dense chunks.
    int ogm = og % 12;
    if (ogm != 8) {
        int ko = (ogm == 0) ? 4 : 0;            // o-offset of the 4 k-channels
        int n  = og / 12;
        float* kt = &xs[0][0];                  // 4480 floats, main-loop xs is dead
        if (wv < WW) {
            int wb = wv >> 2, wl = wv & 3;
            #pragma unroll
            for (int kk = 0; kk < 4; ++kk)
                #pragma unroll
                for (int hy = 0; hy < HT; ++hy)
                    kt[(kk*56 + wb)*20 + hy*4 + wl] = acc[hy][ko + kk];
        }
        __syncthreads();
        if (wv < WW) {
            int wb = wv >> 2, s = wv & 3;
            #pragma unroll
            for (int kk = 0; kk < 4; ++kk) {    // d = kk for these channels
                float4 kvv = *(const float4*)(&kt[(kk*56 + wb)*20 + s*4]);
                *(float4*)(qk + (size_t)(n*8 + 4 + kk)*HWSZ
                               + (size_t)wb*(HH*4) + (size_t)(h0 + s)*4) = kvv;
            }
        }
    }
}

// attention (r4-proven shape): block = (8 i-rows, nd), z = local batch. Thread t
// owns j=t. k read from blocked-transposed kT: one float4 per 4-w step, coalesced.
// q broadcast from LDS (uniform addr). Dot semantics frozen: np.einsum SSE1 — 4
// separate no-fma lanes over ascending w, reduce (s0+s1)+(s2+s3); 0.5f* exact;
// gumbel added last. Argmax: strict >, first j. att pre-zeroed by memset:
// winner-only 1.0f stores (epilogue loop removed vs r4).
__global__ __launch_bounds__(256) void k_attn_ri(const float* __restrict__ qk4,
                                                 const float* __restrict__ gum,
                                                 float* __restrict__ att,
                                                 int* __restrict__ idxout,
                                                 int b0) {
    int i0 = blockIdx.x * 8;
    int nd = blockIdx.y;
    int z  = blockIdx.z;
    int b  = b0 + z;
    const float* qkz = qk4 + (size_t)z*64*HWSZ;
    const float* gumb = gum + (size_t)b*NHD*HH*HH;
    float* attb = att + (size_t)b*NHD*HH*HH;
    int* idxb = idxout + (size_t)b*NHD*HH;
    int n = nd >> 2, d = nd & 3;
    const float* qb = qkz + ((size_t)(n*8 + d)*HH + i0)*WW;
    const float* kT = qkz + (size_t)(n*8 + 4 + d)*HWSZ;   // blocked kT
    __shared__ __align__(16) float qs[8][WW];
    __shared__ float vals[8][256];
    int t = threadIdx.x;
    for (int f = t; f < 8*(WW/4); f += 256) {         // 448 float4
        int r = f / (WW/4), p = (f % (WW/4))*4;
        *(float4*)(&qs[r][p]) = *(const float4*)(qb + (size_t)r*WW + p);
    }
    __syncthreads();
    if (t < WW) {
        float s0[8], s1[8], s2[8], s3[8];
        #pragma unroll
        for (int ii = 0; ii < 8; ++ii) { s0[ii]=0.f; s1[ii]=0.f; s2[ii]=0.f; s3[ii]=0.f; }
        const float* kTt = kT + (size_t)t*4;          // this thread's j-slot
        for (int w = 0; w < WW; w += 4) {
            float4 kc = *(const float4*)(kTt + (size_t)(w >> 2)*(HH*4));
            #pragma unroll
            for (int ii = 0; ii < 8; ++ii) {
                float4 qc = *(const float4*)(&qs[ii][w]);   // uniform addr -> broadcast
                s0[ii] = __fadd_rn(s0[ii], __fmul_rn(qc.x, kc.x));
                s1[ii] = __fadd_rn(s1[ii], __fmul_rn(qc.y, kc.y));
                s2[ii] = __fadd_rn(s2[ii], __fmul_rn(qc.z, kc.z));
                s3[ii] = __fadd_rn(s3[ii], __fmul_rn(qc.w, kc.w));
            }
        }
        #pragma unroll
        for (int ii = 0; ii < 8; ++ii) {
            float dot = __fadd_rn(__fadd_rn(s0[ii], s1[ii]), __fadd_rn(s2[ii], s3[ii]));
            vals[ii][t] = __fadd_rn(__fmul_rn(0.5f, dot),
                                    gumb[((size_t)nd*HH + (i0 + ii))*HH + t]);
        }
    } else {
        #pragma unroll
        for (int ii = 0; ii < 8; ++ii) vals[ii][t] = -INFINITY;
    }
    __syncthreads();
    int ii = t >> 5, jj = t & 31;
    float best = -INFINITY; int bj = 0x7fffffff;
    for (int j = jj; j < 256; j += 32) {              // ascending j: strict > keeps first
        float v = vals[ii][j];
        if (v > best) { best = v; bj = j; }
    }
    for (int off = 16; off > 0; off >>= 1) {
        float v2 = __shfl_down(best, off, 32);
        int   j2 = __shfl_down(bj,   off, 32);
        if (v2 > best || (v2 == best && j2 < bj)) { best = v2; bj = j2; }
    }
    if (jj == 0) {
        idxb[nd*HH + i0 + ii] = bj;
        attb[((size_t)nd*HH + (i0 + ii))*HH + bj] = 1.f;  // winner only; rest memset 0
    }
}

// A2 = W2*gather(v) + b2 per pixel — gather + 32x32 mm done ONCE, A2 written out.
__global__ __launch_bounds__(256) void k_gather_mm(const float* __restrict__ vbuf,
                                                   const int* __restrict__ idx,
                                                   const float* __restrict__ W2g,
                                                   const float* __restrict__ b2g,
                                                   float* __restrict__ A2) {
    int i = blockIdx.x, b = blockIdx.y;
    __shared__ float w2s[OC*OC];
    __shared__ float b2s[OC];
    __shared__ int   id[OC];
    for (int t = threadIdx.x; t < OC*OC; t += blockDim.x) w2s[t] = W2g[t];
    if (threadIdx.x < OC) {
        b2s[threadIdx.x] = b2g[threadIdx.x];
        id[threadIdx.x]  = idx[(b*NHD + threadIdx.x)*HH + i];
    }
    __syncthreads();
    int wv = threadIdx.x;
    if (wv >= WW) return;
    float vals[OC];
    for (int c = 0; c < OC; ++c)
        vals[c] = vbuf[((size_t)(b*OC + c)*HH + id[c])*WW + wv];
    for (int oc = 0; oc < OC; ++oc) {
        float a = b2s[oc];
        for (int c = 0; c < OC; ++c) a = fmaf(w2s[oc*OC + c], vals[c], a);
        A2[((size_t)(b*OC + oc)*HH + i)*WW + wv] = a;
    }
}

// linear float4 reduction over A2 for per-channel sum/sumsq
__global__ __launch_bounds__(256) void k_stats(const float* __restrict__ A2,
                                               float* __restrict__ sums,
                                               float* __restrict__ sumsq) {
    int oc = blockIdx.x, s = blockIdx.y;    // 16 slabs
    int t = threadIdx.x;
    float a = 0.f, a2 = 0.f;
    const int SL = HWSZ/16;                 // 3136
    for (int b = 0; b < NB; ++b) {
        const float* base = A2 + (size_t)(b*OC + oc)*HWSZ + s*SL;
        for (int e = t*4; e < SL; e += 256*4) {
            float4 v = *(const float4*)(base + e);
            a  += v.x + v.y + v.z + v.w;
            a2 += v.x*v.x + v.y*v.y + v.z*v.z + v.w*v.w;
        }
    }
    __shared__ float r1[256], r2[256];
    r1[t] = a; r2[t] = a2;
    __syncthreads();
    for (int st = 128; st > 0; st >>= 1) {
        if (t < st) { r1[t] += r1[t+st]; r2[t] += r2[t+st]; }
        __syncthreads();
    }
    if (t == 0) { atomicAdd(&sums[oc], r1[0]); atomicAdd(&sumsq[oc], r2[0]); }
}

// streaming BN + SiLU + residual, VECTORIZED: 7 float4 per thread (A2/out aligned
// float4; x1 padded read as 4 coalesced scalars). Per-element arithmetic expression
// identical to the r4 scalar version -> bit-exact.
__global__ __launch_bounds__(256) void k_final(const float* __restrict__ A2,
                                               const float* __restrict__ x1,
                                               const float* __restrict__ sums,
                                               const float* __restrict__ sumsq,
                                               const float* __restrict__ gamma,
                                               const float* __restrict__ beta,
                                               float* __restrict__ out) {
    int i = blockIdx.x, b = blockIdx.y;
    __shared__ float mean_s[OC], inv_s[OC], g_s[OC], be_s[OC];
    if (threadIdx.x < OC) {
        int oc = threadIdx.x;
        const float N = (float)(NB*HH*WW);
        float mean = sums[oc]/N;
        float var  = sumsq[oc]/N - mean*mean;
        mean_s[oc] = mean;
        inv_s[oc]  = rsqrtf(var + 1e-5f);
        g_s[oc]    = gamma[oc];
        be_s[oc]   = beta[oc];
    }
    __syncthreads();
    int t = threadIdx.x;
    #pragma unroll
    for (int k = 0; k < 7; ++k) {
        int f = t + k*256;                  // 0..1791 = 32 oc x 56 float4
        int oc = f / 56;
        int p  = (f - oc*56) * 4;
        size_t o = ((size_t)(b*OC + oc)*HH + i)*WW + p;
        float4 a4 = *(const float4*)(A2 + o);
        const float* xp = x1 + ((size_t)(b*OC + oc)*PH + (i+1))*PW + (p+1);
        float m = mean_s[oc], iv = inv_s[oc], g = g_s[oc], be = be_s[oc];
        float4 r;
        { float a = a4.x; float an = (a - m)*iv*g + be;
          float sw = an / (1.f + __expf(-an)); r.x = sw + xp[0]; }
        { float a = a4.y; float an = (a - m)*iv*g + be;
          float sw = an / (1.f + __expf(-an)); r.y = sw + xp[1]; }
        { float a = a4.z; float an = (a - m)*iv*g + be;
          float sw = an / (1.f + __expf(-an)); r.z = sw + xp[2]; }
        { float a = a4.w; float an = (a - m)*iv*g + be;
          float sw = an / (1.f + __expf(-an)); r.w = sw + xp[3]; }
        *(float4*)(out + o) = r;
    }
}

extern "C" void kernel_launch(void* const* d_in, const int* in_sizes, int n_in,
                              void* d_out, int out_size, void* d_ws, size_t ws_size,
                              hipStream_t stream) {
    const float* x      = (const float*)d_in[0];
    const float* gumbel = (const float*)d_in[1];
    const float* in_w   = (const float*)d_in[2];
    const float* in_b   = (const float*)d_in[3];
    const float* qkv_w  = (const float*)d_in[4];
    const float* proj_w = (const float*)d_in[5];
    const float* proj_b = (const float*)d_in[6];
    const float* upd_w  = (const float*)d_in[7];
    const float* upd_b  = (const float*)d_in[8];
    const float* bng    = (const float*)d_in[9];
    const float* bnb    = (const float*)d_in[10];

    float* out = (float*)d_out;
    float* att = out + (size_t)NB*OC*HWSZ;

    // ws layout, total ~155.8 MB. A2 aliases qk4 (both 12,845,056 f) — qk dead after attn.
    float* x1   = (float*)d_ws;                      // 13,191,168 f (52.8 MB, padded)
    float* qk4  = x1 + (size_t)NB*OC*CHS;            // 12,845,056 f (51.4 MB, 4 batches)
    float* A2   = qk4;                               // alias
    float* vbuf = qk4 + (size_t)NGB*64*HWSZ;         // 12,845,056 f (51.4 MB)
    float* W2   = vbuf + (size_t)NB*OC*HWSZ;         // 1024
    float* b2   = W2 + OC*OC;                        // 32
    float* sums = b2 + OC;                           // 32
    float* sumsq= sums + OC;                         // 32
    int*   idx  = (int*)(sumsq + OC);                // 57,344 ints

    hipMemsetAsync(x1, 0, (size_t)NB*OC*CHS*sizeof(float), stream);  // zero pad borders
    hipMemsetAsync(att, 0, (size_t)NB*NHD*HH*HH*sizeof(float), stream); // one-hot base
    hipMemsetAsync(sums, 0, 2*OC*sizeof(float), stream);

    k_w2          <<<1, dim3(OC, OC), 0, stream>>>(proj_w, proj_b, upd_w, upd_b, W2, b2);
    k_conv_in_tile<<<dim3(HH/2, NB), 256, 0, stream>>>(x, in_w, in_b, x1);

    for (int g = 0; g < NB/NGB; ++g) {
        k_conv_qkv_tile<<<dim3(HH/HT, C96/OCT, NGB), 256, 0, stream>>>(
            x1 + (size_t)g*NGB*OC*CHS, qkv_w, qk4, vbuf + (size_t)g*NGB*OC*HWSZ);
        k_attn_ri<<<dim3(HH/8, NHD, NGB), 256, 0, stream>>>(
            qk4, gumbel, att, idx, g*NGB);
    }

    k_gather_mm<<<dim3(HH, NB), 256, 0, stream>>>(vbuf, idx, W2, b2, A2);
    k_stats    <<<dim3(OC, 16), 256, 0, stream>>>(A2, sums, sumsq);
    k_final    <<<dim3(HH, NB), 256, 0, stream>>>(A2, x1, sums, sumsq, bng, bnb, out);
}

// Round 10
// 741.868 us; speedup vs baseline: 1.2062x; 1.0120x over previous
//
#include <hip/hip_runtime.h>
#include <hip/hip_bf16.h>

#define NB 8
#define CIN 3
#define HH 224
#define WW 224
#define OC 32
#define NH 8
#define HD 4
#define NHD 32   // NH*HD
#define C96 96
#define HWSZ (HH*WW)

// padded x1 layout: per channel [PH=226 rows][PW=228 cols], image (h,w) at [h+1][w+1],
// borders zero (one memset). Row stride 228 floats = 912 B (16B-divisible) so any
// row-contiguous tile is one 16B-aligned block -> guard-free direct-to-LDS staging.
#define PH 226
#define PW 228
#define CHS (PH*PW)      // 51528 floats per channel image

#define HT 8     // h rows per block (conv_qkv tile; 4->8 to double FMA per barrier)
#define OCT 8    // output channels per block (proven codegen shape; 12 reg-cliffed)
#define NGB 4    // batches per qkv group dispatch

// k stored in BLOCKED-transposed layout kT[w>>2][h][w&3] (float index
// (w>>2)*896 + h*4 + (w&3), same HWSZ bytes). Each 4h x 4w group is one full
// 64B chunk -> fully dense HBM writes; attn reads float4 per 4-w step.

// direct global->LDS 16B per lane: lds dest is wave-uniform base + lane*16 (HW rule)
__device__ __forceinline__ void gld_lds16(const float* gsrc, float* ldst) {
    __builtin_amdgcn_global_load_lds(
        (const __attribute__((address_space(1))) uint32_t*)gsrc,
        (__attribute__((address_space(3))) uint32_t*)ldst,
        16, 0, 0);
}

// W2 = upd_w @ proj_w ; b2 = upd_w @ proj_b + upd_b   (1x1 conv composition)
__global__ void k_w2(const float* __restrict__ pw, const float* __restrict__ pb,
                     const float* __restrict__ uw, const float* __restrict__ ub,
                     float* __restrict__ W2, float* __restrict__ b2) {
    int c = threadIdx.x, o = threadIdx.y;  // 32x32
    float acc = 0.f;
    for (int m = 0; m < OC; ++m) acc = fmaf(uw[o*OC + m], pw[m*OC + c], acc);
    W2[o*OC + c] = acc;
    if (c == 0) {
        float bb = ub[o];
        for (int m = 0; m < OC; ++m) bb = fmaf(uw[o*OC + m], pb[m], bb);
        b2[o] = bb;
    }
}

// Tiled input conv: block = 2 h-rows x all 32 oc. Stage 3ch x 4 rows in LDS once.
// Per-output order frozen: c asc -> kh -> kw single fmaf chain, bias added after.
// Output written into the PADDED x1 layout (interior only; borders pre-zeroed).
__global__ __launch_bounds__(256) void k_conv_in_tile(const float* __restrict__ x,
                                                      const float* __restrict__ w,
                                                      const float* __restrict__ bias,
                                                      float* __restrict__ x1) {
    int h0 = blockIdx.x * 2;
    int b  = blockIdx.y;
    __shared__ float xs[CIN][4][226];
    int t = threadIdx.x;
    for (int ch = 0; ch < CIN; ++ch)
        for (int r = 0; r < 4; ++r) {
            int gh = h0 - 1 + r;
            for (int col = t; col < 226; col += 256) {
                float v = 0.f;
                if (gh >= 0 && gh < HH && col > 0 && col < 225)
                    v = x[((size_t)(b*CIN + ch)*HH + gh)*WW + (col-1)];
                xs[ch][r][col] = v;
            }
        }
    __syncthreads();
    int wv = t;
    if (wv >= WW) return;
    float xv[CIN][4][3];
    #pragma unroll
    for (int c = 0; c < CIN; ++c)
        #pragma unroll
        for (int r = 0; r < 4; ++r)
            #pragma unroll
            for (int j = 0; j < 3; ++j)
                xv[c][r][j] = xs[c][r][wv + j];
    float acc[2][OC];
    #pragma unroll
    for (int hy = 0; hy < 2; ++hy)
        for (int oc = 0; oc < OC; ++oc) acc[hy][oc] = 0.f;
    #pragma unroll
    for (int c = 0; c < CIN; ++c)
        #pragma unroll
        for (int kh = 0; kh < 3; ++kh)
            #pragma unroll
            for (int kw = 0; kw < 3; ++kw)
                for (int oc = 0; oc < OC; ++oc) {
                    float wgt = w[oc*CIN*9 + c*9 + kh*3 + kw];  // uniform -> s_load
                    #pragma unroll
                    for (int hy = 0; hy < 2; ++hy)
                        acc[hy][oc] = fmaf(xv[c][hy+kh][kw], wgt, acc[hy][oc]);
                }
    for (int oc = 0; oc < OC; ++oc) {
        float bs = bias[oc];
        #pragma unroll
        for (int hy = 0; hy < 2; ++hy)
            x1[((size_t)(b*OC + oc)*PH + (h0+hy+1))*PW + (wv+1)] = __fadd_rn(acc[hy][oc], bs);
    }
}

// Tiled qkv conv, HT=8: double-buffered direct-to-LDS staging (10 rows = 9 x 1KB
// wave-chunks), 576 FMA per thread between barriers (2x r9) to amortize the
// barrier/vmcnt drain. Per-output accumulation order frozen: c asc -> kh -> kw,
// single fmaf chain (hy tiling can't reorder it: acc data dependency serializes).
// k-channels: LDS-assembled blocked-transposed store, two 4-row passes.
__global__ __launch_bounds__(256) void k_conv_qkv_tile(const float* __restrict__ x1g,
                                                       const float* __restrict__ w,
                                                       float* __restrict__ qk4,
                                                       float* __restrict__ vbg) {
    int h0 = blockIdx.x * HT;          // 28 tiles
    int og = blockIdx.y * OCT;         // 12 groups
    int z  = blockIdx.z;               // local batch
    const float* x1b = x1g + (size_t)z*OC*CHS;
    float* qk = qk4 + (size_t)z*64*HWSZ;
    float* vb = vbg + (size_t)z*OC*HWSZ;
    // 2 x 2304 floats (10-row tile = 2280 used, 9 chunks); k-store reuses 4480 flat
    __shared__ float xs[2][2304];
    int t = threadIdx.x;
    int lane = t & 63, wid = t >> 6;
    int wv = t;
    float acc[HT][OCT];
    #pragma unroll
    for (int a = 0; a < HT; ++a)
        #pragma unroll
        for (int o = 0; o < OCT; ++o) acc[a][o] = 0.f;

    // stage c=0 into buf 0 (9 chunks; chunk 8 over-reads 24 floats, never consumed)
    {
        const float* src = x1b + (size_t)h0*PW;
        for (int k = wid; k < 9; k += 4)
            gld_lds16(src + k*256 + lane*4, &xs[0][k*256]);
    }
    __syncthreads();

    for (int c = 0; c < OC; ++c) {
        int cur = c & 1;
        if (c + 1 < OC) {                       // prefetch next channel into other buf
            const float* src = x1b + (size_t)(c+1)*CHS + (size_t)h0*PW;
            float* dst = xs[cur ^ 1];
            for (int k = wid; k < 9; k += 4)
                gld_lds16(src + k*256 + lane*4, dst + k*256);
        }
        if (wv < WW) {
            float xv[HT+2][3];
            #pragma unroll
            for (int r = 0; r < HT+2; ++r)
                #pragma unroll
                for (int j = 0; j < 3; ++j)
                    xv[r][j] = xs[cur][r*PW + wv + j];
            #pragma unroll
            for (int o = 0; o < OCT; ++o) {
                const float* wr = w + ((size_t)(og + o)*OC + c)*9;
                #pragma unroll
                for (int kh = 0; kh < 3; ++kh)
                    #pragma unroll
                    for (int kw = 0; kw < 3; ++kw) {
                        float wgt = wr[kh*3 + kw];
                        #pragma unroll
                        for (int hy = 0; hy < HT; ++hy)
                            acc[hy][o] = fmaf(xv[hy+kh][kw], wgt, acc[hy][o]);
                    }
            }
        }
        __syncthreads();
    }
    // q and v: coalesced row stores
    if (wv < WW) {
        #pragma unroll
        for (int o = 0; o < OCT; ++o) {
            int oc = og + o;
            int rem = oc % 12;
            int r = rem >> 2, d = rem & 3;
            int n = oc / 12;
            if (r == 0) {
                #pragma unroll
                for (int hy = 0; hy < HT; ++hy)
                    qk[((size_t)(n*8 + d)*HH + (h0+hy))*WW + wv] = acc[hy][o];
            } else if (r == 2) {
                #pragma unroll
                for (int hy = 0; hy < HT; ++hy)
                    vb[((size_t)(n*4 + d)*HH + (h0+hy))*WW + wv] = acc[hy][o];
            }
        }
    }
    // k-channels (blocks have 0 or 4): two 4-row LDS passes, 64B-dense stores.
    int ogm = og % 12;                          // block-uniform branch
    if (ogm != 8) {
        int ko = (ogm == 0) ? 4 : 0;            // o-offset of the 4 k-channels
        int n  = og / 12;
        float* kt = &xs[0][0];                  // 4480 floats <= 4608, xs is dead
        #pragma unroll
        for (int g2 = 0; g2 < 2; ++g2) {
            __syncthreads();                    // protect kt reuse across passes
            if (wv < WW) {
                int wb = wv >> 2, wl = wv & 3;
                #pragma unroll
                for (int kk = 0; kk < 4; ++kk)
                    #pragma unroll
                    for (int hh = 0; hh < 4; ++hh)
                        kt[(kk*56 + wb)*20 + hh*4 + wl] = acc[4*g2 + hh][ko + kk];
            }
            __syncthreads();
            if (wv < WW) {
                int wb = wv >> 2, s = wv & 3;
                #pragma unroll
                for (int kk = 0; kk < 4; ++kk) {    // d = kk for these channels
                    float4 kvv = *(const float4*)(&kt[(kk*56 + wb)*20 + s*4]);
                    *(float4*)(qk + (size_t)(n*8 + 4 + kk)*HWSZ
                                   + (size_t)wb*(HH*4) + (size_t)(h0 + 4*g2 + s)*4) = kvv;
                }
            }
        }
    }
}

// attention (r4-proven shape): block = (8 i-rows, nd), z = local batch. Thread t
// owns j=t. k read from blocked-transposed kT: one float4 per 4-w step, coalesced.
// q broadcast from LDS (uniform addr). Dot semantics frozen: np.einsum SSE1 — 4
// separate no-fma lanes over ascending w, reduce (s0+s1)+(s2+s3); 0.5f* exact;
// gumbel added last. Argmax: strict >, first j. att pre-zeroed by memset:
// winner-only 1.0f stores.
__global__ __launch_bounds__(256) void k_attn_ri(const float* __restrict__ qk4,
                                                 const float* __restrict__ gum,
                                                 float* __restrict__ att,
                                                 int* __restrict__ idxout,
                                                 int b0) {
    int i0 = blockIdx.x * 8;
    int nd = blockIdx.y;
    int z  = blockIdx.z;
    int b  = b0 + z;
    const float* qkz = qk4 + (size_t)z*64*HWSZ;
    const float* gumb = gum + (size_t)b*NHD*HH*HH;
    float* attb = att + (size_t)b*NHD*HH*HH;
    int* idxb = idxout + (size_t)b*NHD*HH;
    int n = nd >> 2, d = nd & 3;
    const float* qb = qkz + ((size_t)(n*8 + d)*HH + i0)*WW;
    const float* kT = qkz + (size_t)(n*8 + 4 + d)*HWSZ;   // blocked kT
    __shared__ __align__(16) float qs[8][WW];
    __shared__ float vals[8][256];
    int t = threadIdx.x;
    for (int f = t; f < 8*(WW/4); f += 256) {         // 448 float4
        int r = f / (WW/4), p = (f % (WW/4))*4;
        *(float4*)(&qs[r][p]) = *(const float4*)(qb + (size_t)r*WW + p);
    }
    __syncthreads();
    if (t < WW) {
        float s0[8], s1[8], s2[8], s3[8];
        #pragma unroll
        for (int ii = 0; ii < 8; ++ii) { s0[ii]=0.f; s1[ii]=0.f; s2[ii]=0.f; s3[ii]=0.f; }
        const float* kTt = kT + (size_t)t*4;          // this thread's j-slot
        for (int w = 0; w < WW; w += 4) {
            float4 kc = *(const float4*)(kTt + (size_t)(w >> 2)*(HH*4));
            #pragma unroll
            for (int ii = 0; ii < 8; ++ii) {
                float4 qc = *(const float4*)(&qs[ii][w]);   // uniform addr -> broadcast
                s0[ii] = __fadd_rn(s0[ii], __fmul_rn(qc.x, kc.x));
                s1[ii] = __fadd_rn(s1[ii], __fmul_rn(qc.y, kc.y));
                s2[ii] = __fadd_rn(s2[ii], __fmul_rn(qc.z, kc.z));
                s3[ii] = __fadd_rn(s3[ii], __fmul_rn(qc.w, kc.w));
            }
        }
        #pragma unroll
        for (int ii = 0; ii < 8; ++ii) {
            float dot = __fadd_rn(__fadd_rn(s0[ii], s1[ii]), __fadd_rn(s2[ii], s3[ii]));
            vals[ii][t] = __fadd_rn(__fmul_rn(0.5f, dot),
                                    gumb[((size_t)nd*HH + (i0 + ii))*HH + t]);
        }
    } else {
        #pragma unroll
        for (int ii = 0; ii < 8; ++ii) vals[ii][t] = -INFINITY;
    }
    __syncthreads();
    int ii = t >> 5, jj = t & 31;
    float best = -INFINITY; int bj = 0x7fffffff;
    for (int j = jj; j < 256; j += 32) {              // ascending j: strict > keeps first
        float v = vals[ii][j];
        if (v > best) { best = v; bj = j; }
    }
    for (int off = 16; off > 0; off >>= 1) {
        float v2 = __shfl_down(best, off, 32);
        int   j2 = __shfl_down(bj,   off, 32);
        if (v2 > best || (v2 == best && j2 < bj)) { best = v2; bj = j2; }
    }
    if (jj == 0) {
        idxb[nd*HH + i0 + ii] = bj;
        attb[((size_t)nd*HH + (i0 + ii))*HH + bj] = 1.f;  // winner only; rest memset 0
    }
}

// A2 = W2*gather(v) + b2 per pixel — gather + 32x32 mm done ONCE, A2 written out.
__global__ __launch_bounds__(256) void k_gather_mm(const float* __restrict__ vbuf,
                                                   const int* __restrict__ idx,
                                                   const float* __restrict__ W2g,
                                                   const float* __restrict__ b2g,
                                                   float* __restrict__ A2) {
    int i = blockIdx.x, b = blockIdx.y;
    __shared__ float w2s[OC*OC];
    __shared__ float b2s[OC];
    __shared__ int   id[OC];
    for (int t = threadIdx.x; t < OC*OC; t += blockDim.x) w2s[t] = W2g[t];
    if (threadIdx.x < OC) {
        b2s[threadIdx.x] = b2g[threadIdx.x];
        id[threadIdx.x]  = idx[(b*NHD + threadIdx.x)*HH + i];
    }
    __syncthreads();
    int wv = threadIdx.x;
    if (wv >= WW) return;
    float vals[OC];
    for (int c = 0; c < OC; ++c)
        vals[c] = vbuf[((size_t)(b*OC + c)*HH + id[c])*WW + wv];
    for (int oc = 0; oc < OC; ++oc) {
        float a = b2s[oc];
        for (int c = 0; c < OC; ++c) a = fmaf(w2s[oc*OC + c], vals[c], a);
        A2[((size_t)(b*OC + oc)*HH + i)*WW + wv] = a;
    }
}

// linear float4 reduction over A2 for per-channel sum/sumsq
__global__ __launch_bounds__(256) void k_stats(const float* __restrict__ A2,
                                               float* __restrict__ sums,
                                               float* __restrict__ sumsq) {
    int oc = blockIdx.x, s = blockIdx.y;    // 16 slabs
    int t = threadIdx.x;
    float a = 0.f, a2 = 0.f;
    const int SL = HWSZ/16;                 // 3136
    for (int b = 0; b < NB; ++b) {
        const float* base = A2 + (size_t)(b*OC + oc)*HWSZ + s*SL;
        for (int e = t*4; e < SL; e += 256*4) {
            float4 v = *(const float4*)(base + e);
            a  += v.x + v.y + v.z + v.w;
            a2 += v.x*v.x + v.y*v.y + v.z*v.z + v.w*v.w;
        }
    }
    __shared__ float r1[256], r2[256];
    r1[t] = a; r2[t] = a2;
    __syncthreads();
    for (int st = 128; st > 0; st >>= 1) {
        if (t < st) { r1[t] += r1[t+st]; r2[t] += r2[t+st]; }
        __syncthreads();
    }
    if (t == 0) { atomicAdd(&sums[oc], r1[0]); atomicAdd(&sumsq[oc], r2[0]); }
}

// streaming BN + SiLU + residual, VECTORIZED: 7 float4 per thread (A2/out aligned
// float4; x1 padded read as 4 coalesced scalars). Per-element arithmetic expression
// identical to the scalar version -> bit-exact.
__global__ __launch_bounds__(256) void k_final(const float* __restrict__ A2,
                                               const float* __restrict__ x1,
                                               const float* __restrict__ sums,
                                               const float* __restrict__ sumsq,
                                               const float* __restrict__ gamma,
                                               const float* __restrict__ beta,
                                               float* __restrict__ out) {
    int i = blockIdx.x, b = blockIdx.y;
    __shared__ float mean_s[OC], inv_s[OC], g_s[OC], be_s[OC];
    if (threadIdx.x < OC) {
        int oc = threadIdx.x;
        const float N = (float)(NB*HH*WW);
        float mean = sums[oc]/N;
        float var  = sumsq[oc]/N - mean*mean;
        mean_s[oc] = mean;
        inv_s[oc]  = rsqrtf(var + 1e-5f);
        g_s[oc]    = gamma[oc];
        be_s[oc]   = beta[oc];
    }
    __syncthreads();
    int t = threadIdx.x;
    #pragma unroll
    for (int k = 0; k < 7; ++k) {
        int f = t + k*256;                  // 0..1791 = 32 oc x 56 float4
        int oc = f / 56;
        int p  = (f - oc*56) * 4;
        size_t o = ((size_t)(b*OC + oc)*HH + i)*WW + p;
        float4 a4 = *(const float4*)(A2 + o);
        const float* xp = x1 + ((size_t)(b*OC + oc)*PH + (i+1))*PW + (p+1);
        float m = mean_s[oc], iv = inv_s[oc], g = g_s[oc], be = be_s[oc];
        float4 r;
        { float a = a4.x; float an = (a - m)*iv*g + be;
          float sw = an / (1.f + __expf(-an)); r.x = sw + xp[0]; }
        { float a = a4.y; float an = (a - m)*iv*g + be;
          float sw = an / (1.f + __expf(-an)); r.y = sw + xp[1]; }
        { float a = a4.z; float an = (a - m)*iv*g + be;
          float sw = an / (1.f + __expf(-an)); r.z = sw + xp[2]; }
        { float a = a4.w; float an = (a - m)*iv*g + be;
          float sw = an / (1.f + __expf(-an)); r.w = sw + xp[3]; }
        *(float4*)(out + o) = r;
    }
}

extern "C" void kernel_launch(void* const* d_in, const int* in_sizes, int n_in,
                              void* d_out, int out_size, void* d_ws, size_t ws_size,
                              hipStream_t stream) {
    const float* x      = (const float*)d_in[0];
    const float* gumbel = (const float*)d_in[1];
    const float* in_w   = (const float*)d_in[2];
    const float* in_b   = (const float*)d_in[3];
    const float* qkv_w  = (const float*)d_in[4];
    const float* proj_w = (const float*)d_in[5];
    const float* proj_b = (const float*)d_in[6];
    const float* upd_w  = (const float*)d_in[7];
    const float* upd_b  = (const float*)d_in[8];
    const float* bng    = (const float*)d_in[9];
    const float* bnb    = (const float*)d_in[10];

    float* out = (float*)d_out;
    float* att = out + (size_t)NB*OC*HWSZ;

    // ws layout, total ~155.8 MB. A2 aliases qk4 (both 12,845,056 f) — qk dead after attn.
    float* x1   = (float*)d_ws;                      // 13,191,168 f (52.8 MB, padded)
    float* qk4  = x1 + (size_t)NB*OC*CHS;            // 12,845,056 f (51.4 MB, 4 batches)
    float* A2   = qk4;                               // alias
    float* vbuf = qk4 + (size_t)NGB*64*HWSZ;         // 12,845,056 f (51.4 MB)
    float* W2   = vbuf + (size_t)NB*OC*HWSZ;         // 1024
    float* b2   = W2 + OC*OC;                        // 32
    float* sums = b2 + OC;                           // 32
    float* sumsq= sums + OC;                         // 32
    int*   idx  = (int*)(sumsq + OC);                // 57,344 ints

    hipMemsetAsync(x1, 0, (size_t)NB*OC*CHS*sizeof(float), stream);  // zero pad borders
    hipMemsetAsync(att, 0, (size_t)NB*NHD*HH*HH*sizeof(float), stream); // one-hot base
    hipMemsetAsync(sums, 0, 2*OC*sizeof(float), stream);

    k_w2          <<<1, dim3(OC, OC), 0, stream>>>(proj_w, proj_b, upd_w, upd_b, W2, b2);
    k_conv_in_tile<<<dim3(HH/2, NB), 256, 0, stream>>>(x, in_w, in_b, x1);

    for (int g = 0; g < NB/NGB; ++g) {
        k_conv_qkv_tile<<<dim3(HH/HT, C96/OCT, NGB), 256, 0, stream>>>(
            x1 + (size_t)g*NGB*OC*CHS, qkv_w, qk4, vbuf + (size_t)g*NGB*OC*HWSZ);
        k_attn_ri<<<dim3(HH/8, NHD, NGB), 256, 0, stream>>>(
            qk4, gumbel, att, idx, g*NGB);
    }

    k_gather_mm<<<dim3(HH, NB), 256, 0, stream>>>(vbuf, idx, W2, b2, A2);
    k_stats    <<<dim3(OC, 16), 256, 0, stream>>>(A2, sums, sumsq);
    k_final    <<<dim3(HH, NB), 256, 0, stream>>>(A2, x1, sums, sumsq, bng, bnb, out);
}